// Round 7
// baseline (1783.472 us; speedup 1.0000x reference)
//
#include <hip/hip_runtime.h>
#include <hip/hip_bf16.h>

// Problem constants (match reference)
constexpr int Bn = 16384;
constexpr int S  = 64;
constexpr int H  = 256;
constexpr int E  = 8;

constexpr int RPB    = 32;           // rows per combine chunk
constexpr int NCHUNK = Bn / RPB;     // 512 chunks
constexpr int PSTR   = H + 8;        // 264 bf16 row stride in LDS
constexpr int POOLB  = Bn / 4;       // 4096 pool blocks (4 rows each; 8 per chunk)

typedef short bf16x8 __attribute__((ext_vector_type(8)));
typedef float f32x4  __attribute__((ext_vector_type(4)));

__device__ __forceinline__ float fast_tanh(float x) {
    const float ex = __expf(2.0f * x);
    return (ex - 1.0f) / (ex + 1.0f);
}

// ---------------------------------------------------------------------------
// Prep: Wf fragment-order build (proven round-6 logic) + zero chunk counters.
// Runs as its own launch so stream ordering guarantees Wf/cnt ready for mega.
// Grid: 64 blocks = 8 experts x 8 k-tiles of 32 h. 256 threads.
// ---------------------------------------------------------------------------
__global__ __launch_bounds__(256) void prep_kernel(const float* __restrict__ We,
                                                   __hip_bfloat16* __restrict__ Wf,
                                                   int* __restrict__ cnt) {
    __shared__ __hip_bfloat16 tile[32][H + 4];   // [h_local][d]
    const int bid = blockIdx.x;
    const int t   = threadIdx.x;

    if (bid == 0) {            // zero the 512 chunk counters (replay-safe)
        cnt[t]       = 0;
        cnt[t + 256] = 0;
    }

    const int e  = bid >> 3;
    const int kk = bid & 7;          // k-tile = 32 h rows

    const float* src = We + ((size_t)e * H + kk * 32) * H;   // 32 h-rows x 256 d
#pragma unroll
    for (int i = 0; i < 8; ++i) {
        const int idx = t + 256 * i;    // 0..2047
        const int hh  = idx >> 6;       // 0..31
        const int c4  = idx & 63;
        float4 v = reinterpret_cast<const float4*>(src + (size_t)hh * H)[c4];
        tile[hh][c4 * 4 + 0] = __float2bfloat16(v.x);
        tile[hh][c4 * 4 + 1] = __float2bfloat16(v.y);
        tile[hh][c4 * 4 + 2] = __float2bfloat16(v.z);
        tile[hh][c4 * 4 + 3] = __float2bfloat16(v.w);
    }
    __syncthreads();

    // 1024 16B-chunks, 4 per thread, coalesced dwordx4 stores
#pragma unroll
    for (int i = 0; i < 4; ++i) {
        const int task = i * 256 + t;   // 0..1023
        const int nt_  = task >> 6;     // 0..15
        const int l    = task & 63;
        const int hlb  = (l >> 4) * 8;
        const int d    = nt_ * 16 + (l & 15);
        bf16x8 p;
#pragma unroll
        for (int j = 0; j < 8; ++j) {
            __hip_bfloat16 hv = tile[hlb + j][d];
            p[j] = *reinterpret_cast<short*>(&hv);
        }
        reinterpret_cast<bf16x8*>(Wf)[(((size_t)(e * 8 + kk) * 16 + nt_) * 64 + l)] = p;
    }
}

// ---------------------------------------------------------------------------
// Mega: pool 4 rows (round-6 code, byte-identical) -> fence -> chunk counter.
// The 8th finisher of each 32-row chunk immediately runs the round-6 combine
// for that chunk -> combine overlaps the stream; no post-stream serialization.
// No spinning anywhere -> dispatch-order independent, deadlock-free.
// ---------------------------------------------------------------------------
__global__ __launch_bounds__(256) void mega_kernel(
    const float* __restrict__ x,
    const float* __restrict__ xr,              // [B][H]
    const float* __restrict__ Wr,              // [H][E]
    const float* __restrict__ be,              // [E][H]
    const __hip_bfloat16* __restrict__ Wf,     // fragment-ordered, 1 MiB
    __hip_bfloat16* __restrict__ pws,          // [B][H] bf16
    float* __restrict__ out,                   // [B][H] f32
    int* __restrict__ cnt)                     // [NCHUNK]
{
    const int t = threadIdx.x;

    // ---- pool: 4 rows per block, one wave per row (round-6 verbatim) ----
    {
        const int row = blockIdx.x * 4 + (t >> 6);
        const int c4  = t & 63;

        const f32x4* xrow = reinterpret_cast<const f32x4*>(x + (size_t)row * (S * H));
        f32x4 a0 = 0.f, a1 = 0.f, a2 = 0.f, a3 = 0.f;
#pragma unroll 16
        for (int s = 0; s < S; s += 4) {
            f32x4 v0 = __builtin_nontemporal_load(xrow + (s + 0) * 64 + c4);
            f32x4 v1 = __builtin_nontemporal_load(xrow + (s + 1) * 64 + c4);
            f32x4 v2 = __builtin_nontemporal_load(xrow + (s + 2) * 64 + c4);
            f32x4 v3 = __builtin_nontemporal_load(xrow + (s + 3) * 64 + c4);
            a0 += v0; a1 += v1; a2 += v2; a3 += v3;
        }
        const f32x4 res = (a0 + a1) + (a2 + a3);
        const float sc = 1.0f / (float)S;
        ushort4 pk;
        {
            __hip_bfloat16 h0 = __float2bfloat16(res[0] * sc);
            __hip_bfloat16 h1 = __float2bfloat16(res[1] * sc);
            __hip_bfloat16 h2 = __float2bfloat16(res[2] * sc);
            __hip_bfloat16 h3 = __float2bfloat16(res[3] * sc);
            pk.x = *reinterpret_cast<unsigned short*>(&h0);
            pk.y = *reinterpret_cast<unsigned short*>(&h1);
            pk.z = *reinterpret_cast<unsigned short*>(&h2);
            pk.w = *reinterpret_cast<unsigned short*>(&h3);
        }
        *reinterpret_cast<ushort4*>(pws + (size_t)row * H + c4 * 4) = pk;
    }

    // ---- release + chunk counter; exactly one block becomes the combiner ----
    __threadfence();          // make this thread's pws stores device-visible
    __syncthreads();          // all 4 rows of this block written+fenced
    __shared__ int isLast;
    if (t == 0) {
        const int chunk = blockIdx.x >> 3;
        isLast = (atomicAdd(&cnt[chunk], 1) == 7) ? 1 : 0;
    }
    __syncthreads();
    if (!isLast) return;      // block-uniform -> no divergent-barrier hazard
    __threadfence();          // acquire: other blocks' pws writes now visible

    const int b0 = (blockIdx.x >> 3) * RPB;

    // ---- combine (round-6 verbatim) ----
    __shared__ __hip_bfloat16 pooled[RPB][PSTR];
    __shared__ float logit_s[RPB][E];
    __shared__ float gate_s[RPB][E];

    // stage pooled rows (16 KB, coalesced bf16x8; 64 B per thread)
    {
        const __hip_bfloat16* src = pws + (size_t)b0 * H + t * 32;
#pragma unroll
        for (int u = 0; u < 4; ++u) {
            const int g = t * 32 + u * 8;           // element index 0..8191
            bf16x8 v = *reinterpret_cast<const bf16x8*>(src + u * 8);
            *reinterpret_cast<bf16x8*>(&pooled[g >> 8][g & 255]) = v;
        }
    }

    // routing logits, f64 accumulation (proven) — all 256 threads
    {
        const int r = t >> 3, e = t & 7;
        const float* xrp = xr + (size_t)(b0 + r) * H;
        double acc = 0.0;
#pragma unroll 8
        for (int h = 0; h < H; ++h)
            acc += (double)xrp[h] * (double)Wr[h * E + e];
        logit_s[r][e] = (float)acc;
    }
    __syncthreads();

    // top-2 + softmax -> dense gate (proven)
    if (t < RPB) {
        int i0 = 0; float v0 = logit_s[t][0];
#pragma unroll
        for (int e = 1; e < E; ++e)
            if (logit_s[t][e] > v0) { v0 = logit_s[t][e]; i0 = e; }
        int i1 = -1; float v1 = -3.0e38f;
#pragma unroll
        for (int e = 0; e < E; ++e) {
            if (e == i0) continue;
            if (logit_s[t][e] > v1) { v1 = logit_s[t][e]; i1 = e; }
        }
        const float ex  = expf(v1 - v0);
        const float inv = 1.0f / (1.0f + ex);
#pragma unroll
        for (int e = 0; e < E; ++e) gate_s[t][e] = 0.f;
        gate_s[t][i0] = inv;
        gate_s[t][i1] = ex * inv;
    }
    __syncthreads();

    // dense 8-expert MFMA (2 m-tiles per wave) + tanh + gate combine
    {
        const int dg = t >> 6;          // wave = column group: cols dg*64 .. +63
        const int l  = t & 63;
        const int lr = l & 15;
        const int lq = l >> 4;          // quarter 0..3

        f32x4 oacc[2][4];
#pragma unroll
        for (int m = 0; m < 2; ++m)
#pragma unroll
            for (int n = 0; n < 4; ++n) oacc[m][n] = 0.f;

        const __hip_bfloat16* a0base = &pooled[lr][lq * 8];        // m=0: rows 0..15
        const __hip_bfloat16* a1base = &pooled[16 + lr][lq * 8];   // m=1: rows 16..31
        const bf16x8* wf8 = reinterpret_cast<const bf16x8*>(Wf);

        for (int e = 0; e < E; ++e) {
            f32x4 acc[2][4];
#pragma unroll
            for (int m = 0; m < 2; ++m)
#pragma unroll
                for (int n = 0; n < 4; ++n) acc[m][n] = 0.f;

#pragma unroll
            for (int kk = 0; kk < 8; ++kk) {
                const bf16x8 a0 = *reinterpret_cast<const bf16x8*>(a0base + kk * 32);
                const bf16x8 a1 = *reinterpret_cast<const bf16x8*>(a1base + kk * 32);
                const size_t kb = ((size_t)(e * 8 + kk) * 16 + dg * 4) * 64 + l;
                bf16x8 bfr[4];
#pragma unroll
                for (int n = 0; n < 4; ++n)
                    bfr[n] = wf8[kb + (size_t)n * 64];
#pragma unroll
                for (int n = 0; n < 4; ++n) {
                    acc[0][n] = __builtin_amdgcn_mfma_f32_16x16x32_bf16(a0, bfr[n], acc[0][n], 0, 0, 0);
                    acc[1][n] = __builtin_amdgcn_mfma_f32_16x16x32_bf16(a1, bfr[n], acc[1][n], 0, 0, 0);
                }
            }

            float g[2][4];
#pragma unroll
            for (int m = 0; m < 2; ++m)
#pragma unroll
                for (int j = 0; j < 4; ++j)
                    g[m][j] = gate_s[m * 16 + lq * 4 + j][e];
#pragma unroll
            for (int n = 0; n < 4; ++n) {
                const int d = dg * 64 + n * 16 + lr;
                const float bias = be[e * H + d];
#pragma unroll
                for (int m = 0; m < 2; ++m)
#pragma unroll
                    for (int j = 0; j < 4; ++j)
                        oacc[m][n][j] += g[m][j] * fast_tanh(acc[m][n][j] + bias);
            }
        }

        // C/D layout: col = lane&15 (-> d), row = (lane>>4)*4 + j (-> batch row)
#pragma unroll
        for (int m = 0; m < 2; ++m)
#pragma unroll
            for (int n = 0; n < 4; ++n) {
                const int d = dg * 64 + n * 16 + lr;
#pragma unroll
                for (int j = 0; j < 4; ++j) {
                    const int r = m * 16 + lq * 4 + j;
                    out[(size_t)(b0 + r) * H + d] = oacc[m][n][j];
                }
            }
    }
}

// ---------------------------------------------------------------------------
// Fallback (round-2 kernel, proven correct) if ws is too small.
// ---------------------------------------------------------------------------
__global__ __launch_bounds__(256) void moe_fused_fallback(
    const float* __restrict__ x, const float* __restrict__ xr,
    const float* __restrict__ Wr, const float* __restrict__ We,
    const float* __restrict__ be, float* __restrict__ out)
{
    const int b = blockIdx.x;
    const int t = threadIdx.x;

    __shared__ float  pooled[H];
    __shared__ float  xr_s[H];
    __shared__ float4 red4[4][64];
    __shared__ float  logits_s[E];
    __shared__ int    sel[2];
    __shared__ float  wsel[2];

    {
        const float4* xrow = reinterpret_cast<const float4*>(x + (size_t)b * S * H);
        const int c4 = t & 63;
        const int sg = t >> 6;
        float4 acc = make_float4(0.f, 0.f, 0.f, 0.f);
#pragma unroll
        for (int i = 0; i < 16; ++i) {
            float4 v = xrow[(sg + 4 * i) * 64 + c4];
            acc.x += v.x; acc.y += v.y; acc.z += v.z; acc.w += v.w;
        }
        red4[sg][c4] = acc;
        xr_s[t] = xr[(size_t)b * H + t];
    }
    __syncthreads();
    {
        const float* r0 = reinterpret_cast<const float*>(&red4[0][0]);
        const float* r1 = reinterpret_cast<const float*>(&red4[1][0]);
        const float* r2 = reinterpret_cast<const float*>(&red4[2][0]);
        const float* r3 = reinterpret_cast<const float*>(&red4[3][0]);
        pooled[t] = (r0[t] + r1[t] + r2[t] + r3[t]) * (1.0f / (float)S);
    }
    if (t < E) {
        double acc = 0.0;
        for (int h = 0; h < H; ++h)
            acc += (double)xr_s[h] * (double)Wr[h * E + t];
        logits_s[t] = (float)acc;
    }
    __syncthreads();
    if (t == 0) {
        int i0 = 0; float v0 = logits_s[0];
        for (int e = 1; e < E; ++e)
            if (logits_s[e] > v0) { v0 = logits_s[e]; i0 = e; }
        int i1 = -1; float v1 = -3.0e38f;
        for (int e = 0; e < E; ++e) {
            if (e == i0) continue;
            if (logits_s[e] > v1) { v1 = logits_s[e]; i1 = e; }
        }
        const float ex = expf(v1 - v0);
        const float inv = 1.0f / (1.0f + ex);
        sel[0] = i0; sel[1] = i1;
        wsel[0] = inv; wsel[1] = ex * inv;
    }
    __syncthreads();
    {
        const int   e0 = sel[0], e1 = sel[1];
        const float w0 = wsel[0], w1 = wsel[1];
        const float* W0 = We + (size_t)e0 * H * H + t;
        const float* W1 = We + (size_t)e1 * H * H + t;
        float a0 = be[e0 * H + t];
        float a1 = be[e1 * H + t];
#pragma unroll 8
        for (int h = 0; h < H; ++h) {
            const float p = pooled[h];
            a0 = fmaf(p, W0[(size_t)h * H], a0);
            a1 = fmaf(p, W1[(size_t)h * H], a1);
        }
        out[(size_t)b * H + t] = w0 * tanhf(a0) + w1 * tanhf(a1);
    }
}

extern "C" void kernel_launch(void* const* d_in, const int* in_sizes, int n_in,
                              void* d_out, int out_size, void* d_ws, size_t ws_size,
                              hipStream_t stream) {
    const float* x  = (const float*)d_in[0];   // [B,S,H]
    const float* xr = (const float*)d_in[1];   // [B,H]
    const float* Wr = (const float*)d_in[2];   // [H,E]
    const float* We = (const float*)d_in[3];   // [E,H,H]
    const float* be = (const float*)d_in[4];   // [E,H]
    float* out = (float*)d_out;

    (void)in_sizes; (void)n_in; (void)out_size;

    const size_t wf_bytes  = (size_t)E * H * H * sizeof(__hip_bfloat16);   // 1 MiB
    const size_t pws_bytes = (size_t)Bn * H * sizeof(__hip_bfloat16);      // 8 MiB
    const size_t cnt_bytes = (size_t)NCHUNK * sizeof(int);                 // 2 KiB
    if (ws_size >= wf_bytes + pws_bytes + cnt_bytes) {
        __hip_bfloat16* Wf  = (__hip_bfloat16*)d_ws;
        __hip_bfloat16* pws = (__hip_bfloat16*)((char*)d_ws + wf_bytes);
        int*            cnt = (int*)((char*)d_ws + wf_bytes + pws_bytes);
        prep_kernel<<<E * 8, 256, 0, stream>>>(We, Wf, cnt);
        mega_kernel<<<POOLB, 256, 0, stream>>>(x, xr, Wr, be, Wf, pws, out, cnt);
    } else {
        moe_fused_fallback<<<Bn, 256, 0, stream>>>(x, xr, Wr, We, be, out);
    }
}

// Round 8
// 256.733 us; speedup vs baseline: 6.9468x; 6.9468x over previous
//
#include <hip/hip_runtime.h>
#include <hip/hip_bf16.h>

// Problem constants (match reference)
constexpr int Bn = 16384;
constexpr int S  = 64;
constexpr int H  = 256;
constexpr int E  = 8;

constexpr int RPB   = 32;           // rows per combine block
constexpr int CBLK  = Bn / RPB;     // 512 combine blocks
constexpr int PSTR  = H + 8;        // 264 bf16 row stride in LDS
constexpr int POOLB = Bn / 4;       // 4096 streaming blocks (4 rows each)
constexpr int PREPB = E * 8;        // 64 prep blocks (8 experts x 8 k-tiles of 32 h)

typedef short bf16x8 __attribute__((ext_vector_type(8)));
typedef float f32x4  __attribute__((ext_vector_type(4)));

__device__ __forceinline__ float fast_tanh(float x) {
    const float ex = __expf(2.0f * x);
    return (ex - 1.0f) / (ex + 1.0f);
}

// ---------------------------------------------------------------------------
// Stage 1 (merged, round-6 structure): blocks [0,POOLB) = streaming mean-pool
// (one wave per row, no reduction, PLAIN loads — nt removed this round);
// blocks [POOLB, POOLB+PREPB) = Wf prep in tail scheduler slots.
//
// Wf fragment order: chunk ((e*8+kk)*16 + nt)*64 + lane holds 8 bf16,
// element j = We[e][h = kk*32 + (lane>>4)*8 + j][d = nt*16 + (lane&15)].
// ---------------------------------------------------------------------------
__global__ __launch_bounds__(256) void stage1_kernel(
    const float* __restrict__ x,
    const float* __restrict__ We,
    __hip_bfloat16* __restrict__ pws,
    __hip_bfloat16* __restrict__ Wf)
{
    __shared__ __hip_bfloat16 tile[32][H + 4];   // prep only: [h_local][d], 16.6 KB
    const int t = threadIdx.x;

    if (blockIdx.x < POOLB) {
        // ---- pool: 4 rows per block, one wave per row ----
        const int row = blockIdx.x * 4 + (t >> 6);
        const int c4  = t & 63;

        const f32x4* xrow = reinterpret_cast<const f32x4*>(x + (size_t)row * (S * H));
        f32x4 a0 = 0.f, a1 = 0.f, a2 = 0.f, a3 = 0.f;
#pragma unroll 16
        for (int s = 0; s < S; s += 4) {
            f32x4 v0 = xrow[(s + 0) * 64 + c4];
            f32x4 v1 = xrow[(s + 1) * 64 + c4];
            f32x4 v2 = xrow[(s + 2) * 64 + c4];
            f32x4 v3 = xrow[(s + 3) * 64 + c4];
            a0 += v0; a1 += v1; a2 += v2; a3 += v3;
        }
        const f32x4 res = (a0 + a1) + (a2 + a3);
        const float sc = 1.0f / (float)S;
        ushort4 pk;
        {
            __hip_bfloat16 h0 = __float2bfloat16(res[0] * sc);
            __hip_bfloat16 h1 = __float2bfloat16(res[1] * sc);
            __hip_bfloat16 h2 = __float2bfloat16(res[2] * sc);
            __hip_bfloat16 h3 = __float2bfloat16(res[3] * sc);
            pk.x = *reinterpret_cast<unsigned short*>(&h0);
            pk.y = *reinterpret_cast<unsigned short*>(&h1);
            pk.z = *reinterpret_cast<unsigned short*>(&h2);
            pk.w = *reinterpret_cast<unsigned short*>(&h3);
        }
        *reinterpret_cast<ushort4*>(pws + (size_t)row * H + c4 * 4) = pk;
    } else {
        // ---- prep: one (expert, k-tile) per block (round-6 verbatim) ----
        const int bid = blockIdx.x - POOLB;
        const int e   = bid >> 3;
        const int kk  = bid & 7;          // k-tile = 32 h rows

        const float* src = We + ((size_t)e * H + kk * 32) * H;   // 32 h-rows x 256 d
#pragma unroll
        for (int i = 0; i < 8; ++i) {
            const int idx = t + 256 * i;    // 0..2047
            const int hh  = idx >> 6;       // 0..31
            const int c4  = idx & 63;
            float4 v = reinterpret_cast<const float4*>(src + (size_t)hh * H)[c4];
            tile[hh][c4 * 4 + 0] = __float2bfloat16(v.x);
            tile[hh][c4 * 4 + 1] = __float2bfloat16(v.y);
            tile[hh][c4 * 4 + 2] = __float2bfloat16(v.z);
            tile[hh][c4 * 4 + 3] = __float2bfloat16(v.w);
        }
        __syncthreads();

        // 1024 16B-chunks, 4 per thread, coalesced dwordx4 stores
#pragma unroll
        for (int i = 0; i < 4; ++i) {
            const int task = i * 256 + t;   // 0..1023
            const int nt_  = task >> 6;     // 0..15
            const int l    = task & 63;
            const int hlb  = (l >> 4) * 8;
            const int d    = nt_ * 16 + (l & 15);
            bf16x8 p;
#pragma unroll
            for (int j = 0; j < 8; ++j) {
                __hip_bfloat16 hv = tile[hlb + j][d];
                p[j] = *reinterpret_cast<short*>(&hv);
            }
            reinterpret_cast<bf16x8*>(Wf)[(((size_t)(e * 8 + kk) * 16 + nt_) * 64 + l)] = p;
        }
    }
}

// ---------------------------------------------------------------------------
// Combine: 512 threads / 8 waves. Wave w -> (mg = w>>2, dg = w&3): one m-tile
// (16 rows) x one column group (64 d). Same per-element MFMA op order as
// round 6 -> bit-identical output; 2x waves/CU for L2-latency hiding; the
// mg-pair of waves reads the same Wf lines (L1 dedup on the same CU).
// ---------------------------------------------------------------------------
__global__ __launch_bounds__(512, 2) void combine_kernel(
    const __hip_bfloat16* __restrict__ pws,    // [B][H] bf16
    const float* __restrict__ xr,              // [B][H]
    const float* __restrict__ Wr,              // [H][E]
    const float* __restrict__ be,              // [E][H]
    const __hip_bfloat16* __restrict__ Wf,     // fragment-ordered, 1 MiB
    float* __restrict__ out)                   // [B][H] f32
{
    const int b0 = blockIdx.x * RPB;
    const int t  = threadIdx.x;

    __shared__ __hip_bfloat16 pooled[RPB][PSTR];
    __shared__ float logit_s[RPB][E];
    __shared__ float gate_s[RPB][E];

    // ---- stage pooled rows (16 KB, coalesced bf16x8; 32 B per thread) ----
    {
        const __hip_bfloat16* src = pws + (size_t)b0 * H + t * 16;
#pragma unroll
        for (int u = 0; u < 2; ++u) {
            const int g = t * 16 + u * 8;           // element index 0..8191
            bf16x8 v = *reinterpret_cast<const bf16x8*>(src + u * 8);
            *reinterpret_cast<bf16x8*>(&pooled[g >> 8][g & 255]) = v;
        }
    }

    // ---- routing logits, f64 accumulation (proven) ----
    if (t < RPB * E) {
        const int r = t >> 3, e = t & 7;
        const float* xrp = xr + (size_t)(b0 + r) * H;
        double acc = 0.0;
#pragma unroll 8
        for (int h = 0; h < H; ++h)
            acc += (double)xrp[h] * (double)Wr[h * E + e];
        logit_s[r][e] = (float)acc;
    }
    __syncthreads();

    // ---- top-2 + softmax -> dense gate (proven) ----
    if (t < RPB) {
        int i0 = 0; float v0 = logit_s[t][0];
#pragma unroll
        for (int e = 1; e < E; ++e)
            if (logit_s[t][e] > v0) { v0 = logit_s[t][e]; i0 = e; }
        int i1 = -1; float v1 = -3.0e38f;
#pragma unroll
        for (int e = 0; e < E; ++e) {
            if (e == i0) continue;
            if (logit_s[t][e] > v1) { v1 = logit_s[t][e]; i1 = e; }
        }
        const float ex  = expf(v1 - v0);
        const float inv = 1.0f / (1.0f + ex);
#pragma unroll
        for (int e = 0; e < E; ++e) gate_s[t][e] = 0.f;
        gate_s[t][i0] = inv;
        gate_s[t][i1] = ex * inv;
    }
    __syncthreads();

    // ---- dense 8-expert MFMA (1 m-tile per wave) + tanh + gate combine ----
    {
        const int w  = t >> 6;
        const int l  = t & 63;
        const int mg = w >> 2;          // m-tile: rows mg*16 .. +15
        const int dg = w & 3;           // column group: cols dg*64 .. +63
        const int lr = l & 15;
        const int lq = l >> 4;          // quarter 0..3

        f32x4 oacc[4];
#pragma unroll
        for (int n = 0; n < 4; ++n) oacc[n] = 0.f;

        const __hip_bfloat16* abase = &pooled[mg * 16 + lr][lq * 8];
        const bf16x8* wf8 = reinterpret_cast<const bf16x8*>(Wf);

        for (int e = 0; e < E; ++e) {
            f32x4 acc[4];
#pragma unroll
            for (int n = 0; n < 4; ++n) acc[n] = 0.f;

#pragma unroll
            for (int kk = 0; kk < 8; ++kk) {
                const bf16x8 a = *reinterpret_cast<const bf16x8*>(abase + kk * 32);
                const size_t kb = ((size_t)(e * 8 + kk) * 16 + dg * 4) * 64 + l;
                bf16x8 bfr[4];
#pragma unroll
                for (int n = 0; n < 4; ++n)
                    bfr[n] = wf8[kb + (size_t)n * 64];
#pragma unroll
                for (int n = 0; n < 4; ++n)
                    acc[n] = __builtin_amdgcn_mfma_f32_16x16x32_bf16(a, bfr[n], acc[n], 0, 0, 0);
            }

            float g[4];
#pragma unroll
            for (int j = 0; j < 4; ++j) g[j] = gate_s[mg * 16 + lq * 4 + j][e];
#pragma unroll
            for (int n = 0; n < 4; ++n) {
                const int d = dg * 64 + n * 16 + lr;
                const float bias = be[e * H + d];
#pragma unroll
                for (int j = 0; j < 4; ++j)
                    oacc[n][j] += g[j] * fast_tanh(acc[n][j] + bias);
            }
        }

        // C/D layout: col = lane&15 (-> d), row = (lane>>4)*4 + j (-> batch row)
#pragma unroll
        for (int n = 0; n < 4; ++n) {
            const int d = dg * 64 + n * 16 + lr;
#pragma unroll
            for (int j = 0; j < 4; ++j) {
                const int r = mg * 16 + lq * 4 + j;
                out[(size_t)(b0 + r) * H + d] = oacc[n][j];
            }
        }
    }
}

// ---------------------------------------------------------------------------
// Fallback (round-2 kernel, proven correct) if ws is too small.
// ---------------------------------------------------------------------------
__global__ __launch_bounds__(256) void moe_fused_fallback(
    const float* __restrict__ x, const float* __restrict__ xr,
    const float* __restrict__ Wr, const float* __restrict__ We,
    const float* __restrict__ be, float* __restrict__ out)
{
    const int b = blockIdx.x;
    const int t = threadIdx.x;

    __shared__ float  pooled[H];
    __shared__ float  xr_s[H];
    __shared__ float4 red4[4][64];
    __shared__ float  logits_s[E];
    __shared__ int    sel[2];
    __shared__ float  wsel[2];

    {
        const float4* xrow = reinterpret_cast<const float4*>(x + (size_t)b * S * H);
        const int c4 = t & 63;
        const int sg = t >> 6;
        float4 acc = make_float4(0.f, 0.f, 0.f, 0.f);
#pragma unroll
        for (int i = 0; i < 16; ++i) {
            float4 v = xrow[(sg + 4 * i) * 64 + c4];
            acc.x += v.x; acc.y += v.y; acc.z += v.z; acc.w += v.w;
        }
        red4[sg][c4] = acc;
        xr_s[t] = xr[(size_t)b * H + t];
    }
    __syncthreads();
    {
        const float* r0 = reinterpret_cast<const float*>(&red4[0][0]);
        const float* r1 = reinterpret_cast<const float*>(&red4[1][0]);
        const float* r2 = reinterpret_cast<const float*>(&red4[2][0]);
        const float* r3 = reinterpret_cast<const float*>(&red4[3][0]);
        pooled[t] = (r0[t] + r1[t] + r2[t] + r3[t]) * (1.0f / (float)S);
    }
    if (t < E) {
        double acc = 0.0;
        for (int h = 0; h < H; ++h)
            acc += (double)xr_s[h] * (double)Wr[h * E + t];
        logits_s[t] = (float)acc;
    }
    __syncthreads();
    if (t == 0) {
        int i0 = 0; float v0 = logits_s[0];
        for (int e = 1; e < E; ++e)
            if (logits_s[e] > v0) { v0 = logits_s[e]; i0 = e; }
        int i1 = -1; float v1 = -3.0e38f;
        for (int e = 0; e < E; ++e) {
            if (e == i0) continue;
            if (logits_s[e] > v1) { v1 = logits_s[e]; i1 = e; }
        }
        const float ex = expf(v1 - v0);
        const float inv = 1.0f / (1.0f + ex);
        sel[0] = i0; sel[1] = i1;
        wsel[0] = inv; wsel[1] = ex * inv;
    }
    __syncthreads();
    {
        const int   e0 = sel[0], e1 = sel[1];
        const float w0 = wsel[0], w1 = wsel[1];
        const float* W0 = We + (size_t)e0 * H * H + t;
        const float* W1 = We + (size_t)e1 * H * H + t;
        float a0 = be[e0 * H + t];
        float a1 = be[e1 * H + t];
#pragma unroll 8
        for (int h = 0; h < H; ++h) {
            const float p = pooled[h];
            a0 = fmaf(p, W0[(size_t)h * H], a0);
            a1 = fmaf(p, W1[(size_t)h * H], a1);
        }
        out[(size_t)b * H + t] = w0 * tanhf(a0) + w1 * tanhf(a1);
    }
}

extern "C" void kernel_launch(void* const* d_in, const int* in_sizes, int n_in,
                              void* d_out, int out_size, void* d_ws, size_t ws_size,
                              hipStream_t stream) {
    const float* x  = (const float*)d_in[0];   // [B,S,H]
    const float* xr = (const float*)d_in[1];   // [B,H]
    const float* Wr = (const float*)d_in[2];   // [H,E]
    const float* We = (const float*)d_in[3];   // [E,H,H]
    const float* be = (const float*)d_in[4];   // [E,H]
    float* out = (float*)d_out;

    (void)in_sizes; (void)n_in; (void)out_size;

    const size_t wf_elems = (size_t)E * H * H;                    // 524288 (1 MiB bf16)
    const size_t need = (wf_elems + (size_t)Bn * H) * sizeof(__hip_bfloat16); // 9 MiB
    if (ws_size >= need) {
        __hip_bfloat16* Wf  = (__hip_bfloat16*)d_ws;
        __hip_bfloat16* pws = Wf + wf_elems;
        stage1_kernel<<<POOLB + PREPB, 256, 0, stream>>>(x, We, pws, Wf);
        combine_kernel<<<CBLK, 512, 0, stream>>>(pws, xr, Wr, be, Wf, out);
    } else {
        moe_fused_fallback<<<Bn, 256, 0, stream>>>(x, xr, Wr, We, be, out);
    }
}

// Round 9
// 240.917 us; speedup vs baseline: 7.4029x; 1.0657x over previous
//
#include <hip/hip_runtime.h>
#include <hip/hip_bf16.h>

// Problem constants (match reference)
constexpr int Bn = 16384;
constexpr int S  = 64;
constexpr int H  = 256;
constexpr int E  = 8;

constexpr int RPB   = 32;           // rows per combine block
constexpr int CBLK  = Bn / RPB;     // 512 combine blocks
constexpr int PSTR  = H + 8;        // 264 bf16 row stride in LDS
constexpr int POOLB = Bn / 4;       // 4096 streaming blocks (4 rows each)
constexpr int PREPB = E * 8;        // 64 prep blocks (8 experts x 8 k-tiles of 32 h)

typedef short bf16x8 __attribute__((ext_vector_type(8)));
typedef float f32x4  __attribute__((ext_vector_type(4)));

__device__ __forceinline__ float fast_tanh(float x) {
    const float ex = __expf(2.0f * x);
    return (ex - 1.0f) / (ex + 1.0f);
}

// ---------------------------------------------------------------------------
// Stage 1 (merged): blocks [0, PREPB) = Wf prep (FIRST, so it overlaps the
// pool ramp instead of running as a serial tail); blocks [PREPB, PREPB+POOLB)
// = streaming mean-pool (one wave per row, nontemporal reads, no reduction).
//
// Wf fragment order: chunk ((e*8+kk)*16 + nt)*64 + lane holds 8 bf16,
// element j = We[e][h = kk*32 + (lane>>4)*8 + j][d = nt*16 + (lane&15)].
// ---------------------------------------------------------------------------
__global__ __launch_bounds__(256) void stage1_kernel(
    const float* __restrict__ x,
    const float* __restrict__ We,
    __hip_bfloat16* __restrict__ pws,
    __hip_bfloat16* __restrict__ Wf)
{
    __shared__ __hip_bfloat16 tile[32][H + 4];   // prep only: [h_local][d], 16.6 KB
    const int t = threadIdx.x;

    if (blockIdx.x >= PREPB) {
        // ---- pool: 4 rows per block, one wave per row (round-6 verbatim) ----
        const int row = (blockIdx.x - PREPB) * 4 + (t >> 6);
        const int c4  = t & 63;

        const f32x4* xrow = reinterpret_cast<const f32x4*>(x + (size_t)row * (S * H));
        f32x4 a0 = 0.f, a1 = 0.f, a2 = 0.f, a3 = 0.f;
#pragma unroll 16
        for (int s = 0; s < S; s += 4) {
            f32x4 v0 = __builtin_nontemporal_load(xrow + (s + 0) * 64 + c4);
            f32x4 v1 = __builtin_nontemporal_load(xrow + (s + 1) * 64 + c4);
            f32x4 v2 = __builtin_nontemporal_load(xrow + (s + 2) * 64 + c4);
            f32x4 v3 = __builtin_nontemporal_load(xrow + (s + 3) * 64 + c4);
            a0 += v0; a1 += v1; a2 += v2; a3 += v3;
        }
        const f32x4 res = (a0 + a1) + (a2 + a3);
        const float sc = 1.0f / (float)S;
        ushort4 pk;
        {
            __hip_bfloat16 h0 = __float2bfloat16(res[0] * sc);
            __hip_bfloat16 h1 = __float2bfloat16(res[1] * sc);
            __hip_bfloat16 h2 = __float2bfloat16(res[2] * sc);
            __hip_bfloat16 h3 = __float2bfloat16(res[3] * sc);
            pk.x = *reinterpret_cast<unsigned short*>(&h0);
            pk.y = *reinterpret_cast<unsigned short*>(&h1);
            pk.z = *reinterpret_cast<unsigned short*>(&h2);
            pk.w = *reinterpret_cast<unsigned short*>(&h3);
        }
        *reinterpret_cast<ushort4*>(pws + (size_t)row * H + c4 * 4) = pk;
    } else {
        // ---- prep: one (expert, k-tile) per block (round-6 verbatim) ----
        const int bid = blockIdx.x;
        const int e   = bid >> 3;
        const int kk  = bid & 7;          // k-tile = 32 h rows

        const float* src = We + ((size_t)e * H + kk * 32) * H;   // 32 h-rows x 256 d
#pragma unroll
        for (int i = 0; i < 8; ++i) {
            const int idx = t + 256 * i;    // 0..2047
            const int hh  = idx >> 6;       // 0..31
            const int c4  = idx & 63;
            float4 v = reinterpret_cast<const float4*>(src + (size_t)hh * H)[c4];
            tile[hh][c4 * 4 + 0] = __float2bfloat16(v.x);
            tile[hh][c4 * 4 + 1] = __float2bfloat16(v.y);
            tile[hh][c4 * 4 + 2] = __float2bfloat16(v.z);
            tile[hh][c4 * 4 + 3] = __float2bfloat16(v.w);
        }
        __syncthreads();

        // 1024 16B-chunks, 4 per thread, coalesced dwordx4 stores
#pragma unroll
        for (int i = 0; i < 4; ++i) {
            const int task = i * 256 + t;   // 0..1023
            const int nt_  = task >> 6;     // 0..15
            const int l    = task & 63;
            const int hlb  = (l >> 4) * 8;
            const int d    = nt_ * 16 + (l & 15);
            bf16x8 p;
#pragma unroll
            for (int j = 0; j < 8; ++j) {
                __hip_bfloat16 hv = tile[hlb + j][d];
                p[j] = *reinterpret_cast<short*>(&hv);
            }
            reinterpret_cast<bf16x8*>(Wf)[(((size_t)(e * 8 + kk) * 16 + nt_) * 64 + l)] = p;
        }
    }
}

// ---------------------------------------------------------------------------
// Combine (round-6 verbatim): 256 threads / 4 waves. Wave w = dg (column
// group of 64 d). Each wave computes BOTH m-tiles from ONE B-frag load.
// ---------------------------------------------------------------------------
__global__ __launch_bounds__(256, 2) void combine_kernel(
    const __hip_bfloat16* __restrict__ pws,    // [B][H] bf16
    const float* __restrict__ xr,              // [B][H]
    const float* __restrict__ Wr,              // [H][E]
    const float* __restrict__ be,              // [E][H]
    const __hip_bfloat16* __restrict__ Wf,     // fragment-ordered, 1 MiB
    float* __restrict__ out)                   // [B][H] f32
{
    const int b0 = blockIdx.x * RPB;
    const int t  = threadIdx.x;

    __shared__ __hip_bfloat16 pooled[RPB][PSTR];
    __shared__ float logit_s[RPB][E];
    __shared__ float gate_s[RPB][E];

    // ---- stage pooled rows (16 KB, coalesced bf16x8; 64 B per thread) ----
    {
        const __hip_bfloat16* src = pws + (size_t)b0 * H + t * 32;
#pragma unroll
        for (int u = 0; u < 4; ++u) {
            const int g = t * 32 + u * 8;           // element index 0..8191
            bf16x8 v = *reinterpret_cast<const bf16x8*>(src + u * 8);
            *reinterpret_cast<bf16x8*>(&pooled[g >> 8][g & 255]) = v;
        }
    }

    // ---- routing logits, f64 accumulation (proven) — all 256 threads ----
    {
        const int r = t >> 3, e = t & 7;
        const float* xrp = xr + (size_t)(b0 + r) * H;
        double acc = 0.0;
#pragma unroll 8
        for (int h = 0; h < H; ++h)
            acc += (double)xrp[h] * (double)Wr[h * E + e];
        logit_s[r][e] = (float)acc;
    }
    __syncthreads();

    // ---- top-2 + softmax -> dense gate (proven) ----
    if (t < RPB) {
        int i0 = 0; float v0 = logit_s[t][0];
#pragma unroll
        for (int e = 1; e < E; ++e)
            if (logit_s[t][e] > v0) { v0 = logit_s[t][e]; i0 = e; }
        int i1 = -1; float v1 = -3.0e38f;
#pragma unroll
        for (int e = 0; e < E; ++e) {
            if (e == i0) continue;
            if (logit_s[t][e] > v1) { v1 = logit_s[t][e]; i1 = e; }
        }
        const float ex  = expf(v1 - v0);
        const float inv = 1.0f / (1.0f + ex);
#pragma unroll
        for (int e = 0; e < E; ++e) gate_s[t][e] = 0.f;
        gate_s[t][i0] = inv;
        gate_s[t][i1] = ex * inv;
    }
    __syncthreads();

    // ---- dense 8-expert MFMA (2 m-tiles per wave) + tanh + gate combine ----
    {
        const int dg = t >> 6;          // wave = column group: cols dg*64 .. +63
        const int l  = t & 63;
        const int lr = l & 15;
        const int lq = l >> 4;          // quarter 0..3

        f32x4 oacc[2][4];
#pragma unroll
        for (int m = 0; m < 2; ++m)
#pragma unroll
            for (int n = 0; n < 4; ++n) oacc[m][n] = 0.f;

        const __hip_bfloat16* a0base = &pooled[lr][lq * 8];        // m=0: rows 0..15
        const __hip_bfloat16* a1base = &pooled[16 + lr][lq * 8];   // m=1: rows 16..31
        const bf16x8* wf8 = reinterpret_cast<const bf16x8*>(Wf);

        for (int e = 0; e < E; ++e) {
            f32x4 acc[2][4];
#pragma unroll
            for (int m = 0; m < 2; ++m)
#pragma unroll
                for (int n = 0; n < 4; ++n) acc[m][n] = 0.f;

#pragma unroll
            for (int kk = 0; kk < 8; ++kk) {
                const bf16x8 a0 = *reinterpret_cast<const bf16x8*>(a0base + kk * 32);
                const bf16x8 a1 = *reinterpret_cast<const bf16x8*>(a1base + kk * 32);
                const size_t kb = ((size_t)(e * 8 + kk) * 16 + dg * 4) * 64 + l;
                bf16x8 bfr[4];
#pragma unroll
                for (int n = 0; n < 4; ++n)
                    bfr[n] = wf8[kb + (size_t)n * 64];
#pragma unroll
                for (int n = 0; n < 4; ++n) {
                    acc[0][n] = __builtin_amdgcn_mfma_f32_16x16x32_bf16(a0, bfr[n], acc[0][n], 0, 0, 0);
                    acc[1][n] = __builtin_amdgcn_mfma_f32_16x16x32_bf16(a1, bfr[n], acc[1][n], 0, 0, 0);
                }
            }

            float g[2][4];
#pragma unroll
            for (int m = 0; m < 2; ++m)
#pragma unroll
                for (int j = 0; j < 4; ++j)
                    g[m][j] = gate_s[m * 16 + lq * 4 + j][e];
#pragma unroll
            for (int n = 0; n < 4; ++n) {
                const int d = dg * 64 + n * 16 + lr;
                const float bias = be[e * H + d];
#pragma unroll
                for (int m = 0; m < 2; ++m)
#pragma unroll
                    for (int j = 0; j < 4; ++j)
                        oacc[m][n][j] += g[m][j] * fast_tanh(acc[m][n][j] + bias);
            }
        }

        // C/D layout: col = lane&15 (-> d), row = (lane>>4)*4 + j (-> batch row)
#pragma unroll
        for (int m = 0; m < 2; ++m)
#pragma unroll
            for (int n = 0; n < 4; ++n) {
                const int d = dg * 64 + n * 16 + lr;
#pragma unroll
                for (int j = 0; j < 4; ++j) {
                    const int r = m * 16 + lq * 4 + j;
                    out[(size_t)(b0 + r) * H + d] = oacc[m][n][j];
                }
            }
    }
}

// ---------------------------------------------------------------------------
// Fallback (round-2 kernel, proven correct) if ws is too small.
// ---------------------------------------------------------------------------
__global__ __launch_bounds__(256) void moe_fused_fallback(
    const float* __restrict__ x, const float* __restrict__ xr,
    const float* __restrict__ Wr, const float* __restrict__ We,
    const float* __restrict__ be, float* __restrict__ out)
{
    const int b = blockIdx.x;
    const int t = threadIdx.x;

    __shared__ float  pooled[H];
    __shared__ float  xr_s[H];
    __shared__ float4 red4[4][64];
    __shared__ float  logits_s[E];
    __shared__ int    sel[2];
    __shared__ float  wsel[2];

    {
        const float4* xrow = reinterpret_cast<const float4*>(x + (size_t)b * S * H);
        const int c4 = t & 63;
        const int sg = t >> 6;
        float4 acc = make_float4(0.f, 0.f, 0.f, 0.f);
#pragma unroll
        for (int i = 0; i < 16; ++i) {
            float4 v = xrow[(sg + 4 * i) * 64 + c4];
            acc.x += v.x; acc.y += v.y; acc.z += v.z; acc.w += v.w;
        }
        red4[sg][c4] = acc;
        xr_s[t] = xr[(size_t)b * H + t];
    }
    __syncthreads();
    {
        const float* r0 = reinterpret_cast<const float*>(&red4[0][0]);
        const float* r1 = reinterpret_cast<const float*>(&red4[1][0]);
        const float* r2 = reinterpret_cast<const float*>(&red4[2][0]);
        const float* r3 = reinterpret_cast<const float*>(&red4[3][0]);
        pooled[t] = (r0[t] + r1[t] + r2[t] + r3[t]) * (1.0f / (float)S);
    }
    if (t < E) {
        double acc = 0.0;
        for (int h = 0; h < H; ++h)
            acc += (double)xr_s[h] * (double)Wr[h * E + t];
        logits_s[t] = (float)acc;
    }
    __syncthreads();
    if (t == 0) {
        int i0 = 0; float v0 = logits_s[0];
        for (int e = 1; e < E; ++e)
            if (logits_s[e] > v0) { v0 = logits_s[e]; i0 = e; }
        int i1 = -1; float v1 = -3.0e38f;
        for (int e = 0; e < E; ++e) {
            if (e == i0) continue;
            if (logits_s[e] > v1) { v1 = logits_s[e]; i1 = e; }
        }
        const float ex = expf(v1 - v0);
        const float inv = 1.0f / (1.0f + ex);
        sel[0] = i0; sel[1] = i1;
        wsel[0] = inv; wsel[1] = ex * inv;
    }
    __syncthreads();
    {
        const int   e0 = sel[0], e1 = sel[1];
        const float w0 = wsel[0], w1 = wsel[1];
        const float* W0 = We + (size_t)e0 * H * H + t;
        const float* W1 = We + (size_t)e1 * H * H + t;
        float a0 = be[e0 * H + t];
        float a1 = be[e1 * H + t];
#pragma unroll 8
        for (int h = 0; h < H; ++h) {
            const float p = pooled[h];
            a0 = fmaf(p, W0[(size_t)h * H], a0);
            a1 = fmaf(p, W1[(size_t)h * H], a1);
        }
        out[(size_t)b * H + t] = w0 * tanhf(a0) + w1 * tanhf(a1);
    }
}

extern "C" void kernel_launch(void* const* d_in, const int* in_sizes, int n_in,
                              void* d_out, int out_size, void* d_ws, size_t ws_size,
                              hipStream_t stream) {
    const float* x  = (const float*)d_in[0];   // [B,S,H]
    const float* xr = (const float*)d_in[1];   // [B,H]
    const float* Wr = (const float*)d_in[2];   // [H,E]
    const float* We = (const float*)d_in[3];   // [E,H,H]
    const float* be = (const float*)d_in[4];   // [E,H]
    float* out = (float*)d_out;

    (void)in_sizes; (void)n_in; (void)out_size;

    const size_t wf_elems = (size_t)E * H * H;                    // 524288 (1 MiB bf16)
    const size_t need = (wf_elems + (size_t)Bn * H) * sizeof(__hip_bfloat16); // 9 MiB
    if (ws_size >= need) {
        __hip_bfloat16* Wf  = (__hip_bfloat16*)d_ws;
        __hip_bfloat16* pws = Wf + wf_elems;
        stage1_kernel<<<POOLB + PREPB, 256, 0, stream>>>(x, We, pws, Wf);
        combine_kernel<<<CBLK, 256, 0, stream>>>(pws, xr, Wr, be, Wf, out);
    } else {
        moe_fused_fallback<<<Bn, 256, 0, stream>>>(x, xr, Wr, We, be, out);
    }
}

// Round 10
// 230.936 us; speedup vs baseline: 7.7228x; 1.0432x over previous
//
#include <hip/hip_runtime.h>
#include <hip/hip_bf16.h>

// Problem constants (match reference)
constexpr int Bn = 16384;
constexpr int S  = 64;
constexpr int H  = 256;
constexpr int E  = 8;

constexpr int RPB   = 64;           // rows per combine block (doubled this round)
constexpr int CBLK  = Bn / RPB;     // 256 combine blocks -> 1/CU, Wf traffic halved
constexpr int PSTR  = H + 8;        // 264 bf16 row stride in LDS
constexpr int POOLB = Bn / 4;       // 4096 streaming blocks (4 rows each)
constexpr int PREPB = E * 8;        // 64 prep blocks (8 experts x 8 k-tiles of 32 h)

typedef short bf16x8 __attribute__((ext_vector_type(8)));
typedef float f32x4  __attribute__((ext_vector_type(4)));

__device__ __forceinline__ float fast_tanh(float x) {
    const float ex = __expf(2.0f * x);
    return (ex - 1.0f) / (ex + 1.0f);
}

// ---------------------------------------------------------------------------
// Stage 1 (byte-identical to round 9): blocks [0, PREPB) = Wf prep; blocks
// [PREPB, PREPB+POOLB) = streaming mean-pool (one wave per row, nt reads).
//
// Wf fragment order: chunk ((e*8+kk)*16 + nt)*64 + lane holds 8 bf16,
// element j = We[e][h = kk*32 + (lane>>4)*8 + j][d = nt*16 + (lane&15)].
// ---------------------------------------------------------------------------
__global__ __launch_bounds__(256) void stage1_kernel(
    const float* __restrict__ x,
    const float* __restrict__ We,
    __hip_bfloat16* __restrict__ pws,
    __hip_bfloat16* __restrict__ Wf)
{
    __shared__ __hip_bfloat16 tile[32][H + 4];   // prep only: [h_local][d], 16.6 KB
    const int t = threadIdx.x;

    if (blockIdx.x >= PREPB) {
        // ---- pool: 4 rows per block, one wave per row ----
        const int row = (blockIdx.x - PREPB) * 4 + (t >> 6);
        const int c4  = t & 63;

        const f32x4* xrow = reinterpret_cast<const f32x4*>(x + (size_t)row * (S * H));
        f32x4 a0 = 0.f, a1 = 0.f, a2 = 0.f, a3 = 0.f;
#pragma unroll 16
        for (int s = 0; s < S; s += 4) {
            f32x4 v0 = __builtin_nontemporal_load(xrow + (s + 0) * 64 + c4);
            f32x4 v1 = __builtin_nontemporal_load(xrow + (s + 1) * 64 + c4);
            f32x4 v2 = __builtin_nontemporal_load(xrow + (s + 2) * 64 + c4);
            f32x4 v3 = __builtin_nontemporal_load(xrow + (s + 3) * 64 + c4);
            a0 += v0; a1 += v1; a2 += v2; a3 += v3;
        }
        const f32x4 res = (a0 + a1) + (a2 + a3);
        const float sc = 1.0f / (float)S;
        ushort4 pk;
        {
            __hip_bfloat16 h0 = __float2bfloat16(res[0] * sc);
            __hip_bfloat16 h1 = __float2bfloat16(res[1] * sc);
            __hip_bfloat16 h2 = __float2bfloat16(res[2] * sc);
            __hip_bfloat16 h3 = __float2bfloat16(res[3] * sc);
            pk.x = *reinterpret_cast<unsigned short*>(&h0);
            pk.y = *reinterpret_cast<unsigned short*>(&h1);
            pk.z = *reinterpret_cast<unsigned short*>(&h2);
            pk.w = *reinterpret_cast<unsigned short*>(&h3);
        }
        *reinterpret_cast<ushort4*>(pws + (size_t)row * H + c4 * 4) = pk;
    } else {
        // ---- prep: one (expert, k-tile) per block ----
        const int bid = blockIdx.x;
        const int e   = bid >> 3;
        const int kk  = bid & 7;          // k-tile = 32 h rows

        const float* src = We + ((size_t)e * H + kk * 32) * H;   // 32 h-rows x 256 d
#pragma unroll
        for (int i = 0; i < 8; ++i) {
            const int idx = t + 256 * i;    // 0..2047
            const int hh  = idx >> 6;       // 0..31
            const int c4  = idx & 63;
            float4 v = reinterpret_cast<const float4*>(src + (size_t)hh * H)[c4];
            tile[hh][c4 * 4 + 0] = __float2bfloat16(v.x);
            tile[hh][c4 * 4 + 1] = __float2bfloat16(v.y);
            tile[hh][c4 * 4 + 2] = __float2bfloat16(v.z);
            tile[hh][c4 * 4 + 3] = __float2bfloat16(v.w);
        }
        __syncthreads();

        // 1024 16B-chunks, 4 per thread, coalesced dwordx4 stores
#pragma unroll
        for (int i = 0; i < 4; ++i) {
            const int task = i * 256 + t;   // 0..1023
            const int nt_  = task >> 6;     // 0..15
            const int l    = task & 63;
            const int hlb  = (l >> 4) * 8;
            const int d    = nt_ * 16 + (l & 15);
            bf16x8 p;
#pragma unroll
            for (int j = 0; j < 8; ++j) {
                __hip_bfloat16 hv = tile[hlb + j][d];
                p[j] = *reinterpret_cast<short*>(&hv);
            }
            reinterpret_cast<bf16x8*>(Wf)[(((size_t)(e * 8 + kk) * 16 + nt_) * 64 + l)] = p;
        }
    }
}

// ---------------------------------------------------------------------------
// Combine: RPB=64 rows/block, 512 threads / 8 waves. Wave w = (mg = w>>2,
// dg = w&3): rows [mg*32, mg*32+32) x cols [dg*64, dg*64+64), as two m-tiles
// from ONE B-frag load (identical per-element op order as round 6 -> bit-
// identical output). 256 blocks -> 1/CU; Wf L2 traffic halved to 256 MB.
// ---------------------------------------------------------------------------
__global__ __launch_bounds__(512, 2) void combine_kernel(
    const __hip_bfloat16* __restrict__ pws,    // [B][H] bf16
    const float* __restrict__ xr,              // [B][H]
    const float* __restrict__ Wr,              // [H][E]
    const float* __restrict__ be,              // [E][H]
    const __hip_bfloat16* __restrict__ Wf,     // fragment-ordered, 1 MiB
    float* __restrict__ out)                   // [B][H] f32
{
    const int b0 = blockIdx.x * RPB;
    const int t  = threadIdx.x;

    __shared__ __hip_bfloat16 pooled[RPB][PSTR];   // 64 x 264 bf16 = 33.8 KB
    __shared__ float logit_s[RPB][E];
    __shared__ float gate_s[RPB][E];

    // ---- stage pooled rows (32 KB, coalesced bf16x8; 64 B per thread) ----
    {
        const __hip_bfloat16* src = pws + (size_t)b0 * H + t * 32;
#pragma unroll
        for (int u = 0; u < 4; ++u) {
            const int g = t * 32 + u * 8;           // element index 0..16383
            bf16x8 v = *reinterpret_cast<const bf16x8*>(src + u * 8);
            *reinterpret_cast<bf16x8*>(&pooled[g >> 8][g & 255]) = v;
        }
    }

    // ---- routing logits, f64 accumulation (proven) — one dot per thread ----
    {
        const int r = t >> 3, e = t & 7;            // r in 0..63
        const float* xrp = xr + (size_t)(b0 + r) * H;
        double acc = 0.0;
#pragma unroll 8
        for (int h = 0; h < H; ++h)
            acc += (double)xrp[h] * (double)Wr[h * E + e];
        logit_s[r][e] = (float)acc;
    }
    __syncthreads();

    // ---- top-2 + softmax -> dense gate (proven) ----
    if (t < RPB) {
        int i0 = 0; float v0 = logit_s[t][0];
#pragma unroll
        for (int e = 1; e < E; ++e)
            if (logit_s[t][e] > v0) { v0 = logit_s[t][e]; i0 = e; }
        int i1 = -1; float v1 = -3.0e38f;
#pragma unroll
        for (int e = 0; e < E; ++e) {
            if (e == i0) continue;
            if (logit_s[t][e] > v1) { v1 = logit_s[t][e]; i1 = e; }
        }
        const float ex  = expf(v1 - v0);
        const float inv = 1.0f / (1.0f + ex);
#pragma unroll
        for (int e = 0; e < E; ++e) gate_s[t][e] = 0.f;
        gate_s[t][i0] = inv;
        gate_s[t][i1] = ex * inv;
    }
    __syncthreads();

    // ---- dense 8-expert MFMA (2 m-tiles per wave) + tanh + gate combine ----
    {
        const int w  = t >> 6;
        const int l  = t & 63;
        const int mg = w >> 2;          // row half: rows mg*32 .. +31
        const int dg = w & 3;           // column group: cols dg*64 .. +63
        const int lr = l & 15;
        const int lq = l >> 4;          // quarter 0..3
        const int r0 = mg * 32;         // base row of this wave's half

        f32x4 oacc[2][4];
#pragma unroll
        for (int m = 0; m < 2; ++m)
#pragma unroll
            for (int n = 0; n < 4; ++n) oacc[m][n] = 0.f;

        const __hip_bfloat16* a0base = &pooled[r0 + lr][lq * 8];        // m=0
        const __hip_bfloat16* a1base = &pooled[r0 + 16 + lr][lq * 8];   // m=1
        const bf16x8* wf8 = reinterpret_cast<const bf16x8*>(Wf);

        for (int e = 0; e < E; ++e) {
            f32x4 acc[2][4];
#pragma unroll
            for (int m = 0; m < 2; ++m)
#pragma unroll
                for (int n = 0; n < 4; ++n) acc[m][n] = 0.f;

#pragma unroll
            for (int kk = 0; kk < 8; ++kk) {
                const bf16x8 a0 = *reinterpret_cast<const bf16x8*>(a0base + kk * 32);
                const bf16x8 a1 = *reinterpret_cast<const bf16x8*>(a1base + kk * 32);
                const size_t kb = ((size_t)(e * 8 + kk) * 16 + dg * 4) * 64 + l;
                bf16x8 bfr[4];
#pragma unroll
                for (int n = 0; n < 4; ++n)
                    bfr[n] = wf8[kb + (size_t)n * 64];
#pragma unroll
                for (int n = 0; n < 4; ++n) {
                    acc[0][n] = __builtin_amdgcn_mfma_f32_16x16x32_bf16(a0, bfr[n], acc[0][n], 0, 0, 0);
                    acc[1][n] = __builtin_amdgcn_mfma_f32_16x16x32_bf16(a1, bfr[n], acc[1][n], 0, 0, 0);
                }
            }

            float g[2][4];
#pragma unroll
            for (int m = 0; m < 2; ++m)
#pragma unroll
                for (int j = 0; j < 4; ++j)
                    g[m][j] = gate_s[r0 + m * 16 + lq * 4 + j][e];
#pragma unroll
            for (int n = 0; n < 4; ++n) {
                const int d = dg * 64 + n * 16 + lr;
                const float bias = be[e * H + d];
#pragma unroll
                for (int m = 0; m < 2; ++m)
#pragma unroll
                    for (int j = 0; j < 4; ++j)
                        oacc[m][n][j] += g[m][j] * fast_tanh(acc[m][n][j] + bias);
            }
        }

        // C/D layout: col = lane&15 (-> d), row = (lane>>4)*4 + j (-> batch row)
#pragma unroll
        for (int m = 0; m < 2; ++m)
#pragma unroll
            for (int n = 0; n < 4; ++n) {
                const int d = dg * 64 + n * 16 + lr;
#pragma unroll
                for (int j = 0; j < 4; ++j) {
                    const int r = r0 + m * 16 + lq * 4 + j;
                    out[(size_t)(b0 + r) * H + d] = oacc[m][n][j];
                }
            }
    }
}

// ---------------------------------------------------------------------------
// Fallback (round-2 kernel, proven correct) if ws is too small.
// ---------------------------------------------------------------------------
__global__ __launch_bounds__(256) void moe_fused_fallback(
    const float* __restrict__ x, const float* __restrict__ xr,
    const float* __restrict__ Wr, const float* __restrict__ We,
    const float* __restrict__ be, float* __restrict__ out)
{
    const int b = blockIdx.x;
    const int t = threadIdx.x;

    __shared__ float  pooled[H];
    __shared__ float  xr_s[H];
    __shared__ float4 red4[4][64];
    __shared__ float  logits_s[E];
    __shared__ int    sel[2];
    __shared__ float  wsel[2];

    {
        const float4* xrow = reinterpret_cast<const float4*>(x + (size_t)b * S * H);
        const int c4 = t & 63;
        const int sg = t >> 6;
        float4 acc = make_float4(0.f, 0.f, 0.f, 0.f);
#pragma unroll
        for (int i = 0; i < 16; ++i) {
            float4 v = xrow[(sg + 4 * i) * 64 + c4];
            acc.x += v.x; acc.y += v.y; acc.z += v.z; acc.w += v.w;
        }
        red4[sg][c4] = acc;
        xr_s[t] = xr[(size_t)b * H + t];
    }
    __syncthreads();
    {
        const float* r0 = reinterpret_cast<const float*>(&red4[0][0]);
        const float* r1 = reinterpret_cast<const float*>(&red4[1][0]);
        const float* r2 = reinterpret_cast<const float*>(&red4[2][0]);
        const float* r3 = reinterpret_cast<const float*>(&red4[3][0]);
        pooled[t] = (r0[t] + r1[t] + r2[t] + r3[t]) * (1.0f / (float)S);
    }
    if (t < E) {
        double acc = 0.0;
        for (int h = 0; h < H; ++h)
            acc += (double)xr_s[h] * (double)Wr[h * E + t];
        logits_s[t] = (float)acc;
    }
    __syncthreads();
    if (t == 0) {
        int i0 = 0; float v0 = logits_s[0];
        for (int e = 1; e < E; ++e)
            if (logits_s[e] > v0) { v0 = logits_s[e]; i0 = e; }
        int i1 = -1; float v1 = -3.0e38f;
        for (int e = 0; e < E; ++e) {
            if (e == i0) continue;
            if (logits_s[e] > v1) { v1 = logits_s[e]; i1 = e; }
        }
        const float ex = expf(v1 - v0);
        const float inv = 1.0f / (1.0f + ex);
        sel[0] = i0; sel[1] = i1;
        wsel[0] = inv; wsel[1] = ex * inv;
    }
    __syncthreads();
    {
        const int   e0 = sel[0], e1 = sel[1];
        const float w0 = wsel[0], w1 = wsel[1];
        const float* W0 = We + (size_t)e0 * H * H + t;
        const float* W1 = We + (size_t)e1 * H * H + t;
        float a0 = be[e0 * H + t];
        float a1 = be[e1 * H + t];
#pragma unroll 8
        for (int h = 0; h < H; ++h) {
            const float p = pooled[h];
            a0 = fmaf(p, W0[(size_t)h * H], a0);
            a1 = fmaf(p, W1[(size_t)h * H], a1);
        }
        out[(size_t)b * H + t] = w0 * tanhf(a0) + w1 * tanhf(a1);
    }
}

extern "C" void kernel_launch(void* const* d_in, const int* in_sizes, int n_in,
                              void* d_out, int out_size, void* d_ws, size_t ws_size,
                              hipStream_t stream) {
    const float* x  = (const float*)d_in[0];   // [B,S,H]
    const float* xr = (const float*)d_in[1];   // [B,H]
    const float* Wr = (const float*)d_in[2];   // [H,E]
    const float* We = (const float*)d_in[3];   // [E,H,H]
    const float* be = (const float*)d_in[4];   // [E,H]
    float* out = (float*)d_out;

    (void)in_sizes; (void)n_in; (void)out_size;

    const size_t wf_elems = (size_t)E * H * H;                    // 524288 (1 MiB bf16)
    const size_t need = (wf_elems + (size_t)Bn * H) * sizeof(__hip_bfloat16); // 9 MiB
    if (ws_size >= need) {
        __hip_bfloat16* Wf  = (__hip_bfloat16*)d_ws;
        __hip_bfloat16* pws = Wf + wf_elems;
        stage1_kernel<<<POOLB + PREPB, 256, 0, stream>>>(x, We, pws, Wf);
        combine_kernel<<<CBLK, 512, 0, stream>>>(pws, xr, Wr, be, Wf, out);
    } else {
        moe_fused_fallback<<<Bn, 256, 0, stream>>>(x, xr, Wr, We, be, out);
    }
}